// Round 16
// baseline (178.170 us; speedup 1.0000x reference)
//
#include <hip/hip_runtime.h>
#include <hip/hip_fp16.h>

// Problem constants
#define BB 4
#define CC 256
#define LL 4096
#define MM 16384   // BB*LL rows
#define KK 4096    // codebook size
#define MARGIN 1.0e-4f

typedef _Float16 half8 __attribute__((ext_vector_type(8)));
typedef _Float16 half4_ __attribute__((ext_vector_type(4)));
typedef float f32x4 __attribute__((ext_vector_type(4)));

#define GLOAD16(gp, lp) __builtin_amdgcn_global_load_lds( \
    (const __attribute__((address_space(1))) void*)(gp),  \
    (__attribute__((address_space(3))) void*)(lp), 16, 0, 0)

// ---------------------------------------------------------------------------
// Fused prep: blocks [0,512) transpose x -> xh fp16 + numpy xsq;
//             blocks [512,1536) pack eh fp16 + numpy esq.  block 256.
__global__ void vq_prep(const float* __restrict__ x, const float* __restrict__ emb,
                        _Float16* __restrict__ xh, float* __restrict__ xsq,
                        _Float16* __restrict__ eh, float* __restrict__ esq) {
  __shared__ float tl[32][260];
  const int t = threadIdx.x;
  if (blockIdx.x < 512) {
    const int b = blockIdx.x >> 7, l0 = (blockIdx.x & 127) * 32;
    const float* src = x + (size_t)b * CC * LL + l0;
#pragma unroll
    for (int it = 0; it < 32; ++it) {
      const int idx = it * 256 + t;
      const int c = idx >> 5, l = idx & 31;
      tl[l][c] = src[(size_t)c * LL + l];
    }
    __syncthreads();
#pragma unroll
    for (int it = 0; it < 4; ++it) {
      const int u = it * 256 + t;
      const int l = u >> 5, c8 = (u & 31) * 8;
      half8 h;
#pragma unroll
      for (int j = 0; j < 8; ++j) h[j] = (_Float16)tl[l][c8 + j];
      *(half8*)(xh + ((size_t)(b * LL + l0 + l)) * CC + c8) = h;
    }
    if (t < 32) {
      float S[2];
#pragma unroll
      for (int blk = 0; blk < 2; ++blk) {
        float v[16];
#pragma unroll
        for (int ln = 0; ln < 16; ++ln) {
          float q[8];
#pragma unroll
          for (int j = 0; j < 8; ++j) {
            const float xv = tl[t][blk * 128 + j * 16 + ln];
            q[j] = xv * xv;
          }
          v[ln] = ((q[0] + q[1]) + (q[2] + q[3])) + ((q[4] + q[5]) + (q[6] + q[7]));
        }
        float s1[8], s2[4], s3[2];
#pragma unroll
        for (int ln = 0; ln < 8; ++ln) s1[ln] = v[ln] + v[ln + 8];
#pragma unroll
        for (int ln = 0; ln < 4; ++ln) s2[ln] = s1[ln] + s1[ln + 4];
#pragma unroll
        for (int ln = 0; ln < 2; ++ln) s3[ln] = s2[ln] + s2[ln + 2];
        S[blk] = s3[0] + s3[1];
      }
      xsq[b * LL + l0 + t] = S[0] + S[1];
    }
  } else {
    const int lane = t & 63, w = t >> 6;
    const int q = (blockIdx.x - 512) * 4 + w;
    const float4 v = ((const float4*)(emb + (size_t)q * CC))[lane];
    float vv[4] = {v.x, v.y, v.z, v.w};
    _Float16 h[4];
#pragma unroll
    for (int i = 0; i < 4; ++i) h[i] = (_Float16)(vv[i] * 4096.0f);
    *(half4_*)(eh + (size_t)q * CC + lane * 4) = half4_{h[0], h[1], h[2], h[3]};
    if (lane == 0) {
      const float* pe = emb + (size_t)q * CC;
      float S[2];
#pragma unroll
      for (int blk = 0; blk < 2; ++blk) {
        float vt[16];
#pragma unroll
        for (int ln = 0; ln < 16; ++ln) {
          float qq[8];
#pragma unroll
          for (int j = 0; j < 8; ++j) {
            const float ev = pe[blk * 128 + j * 16 + ln];
            qq[j] = ev * ev;
          }
          vt[ln] = ((qq[0] + qq[1]) + (qq[2] + qq[3])) + ((qq[4] + qq[5]) + (qq[6] + qq[7]));
        }
        float s1[8], s2[4], s3[2];
#pragma unroll
        for (int ln = 0; ln < 8; ++ln) s1[ln] = vt[ln] + vt[ln + 8];
#pragma unroll
        for (int ln = 0; ln < 4; ++ln) s2[ln] = s1[ln] + s1[ln + 4];
#pragma unroll
        for (int ln = 0; ln < 2; ++ln) s3[ln] = s2[ln] + s2[ln + 2];
        S[blk] = s3[0] + s3[1];
      }
      esq[q] = S[0] + S[1];
    }
  }
}

// ---------------------------------------------------------------------------
// GEMM (r15 main loop + wave-private barrier-free epilogue):
// 128x128 tile, 4 waves, 3 rotating 16KB LDS buffers (depth-2), counted
// vmcnt, ONE barrier per K-step. After the loop: ONE barrier, then each wave
// transposes its own 64x64 quadrant through a private 8KB slice (2 chunks of
// 32 rows) with wave-local lgkmcnt only -> NT stores free-run per wave.
// Partials [M][64] per wave quadrant (r8-proven scheme).
// grid (M/128, K/128) = (128, 32), block 256 (4 waves, 2x2)
__global__ __launch_bounds__(256) void vq_gemm(
    const _Float16* __restrict__ xh, const _Float16* __restrict__ eh,
    const float* __restrict__ xsq, const float* __restrict__ esq,
    float* __restrict__ out,
    float* __restrict__ ps1, int* __restrict__ pi1, float* __restrict__ ps2) {
  __shared__ __align__(16) char smem[49152];

  const int t = threadIdx.x, lane = t & 63, wid = t >> 6;
  const int wm = wid >> 1, wn = wid & 1;
  const int m0 = blockIdx.x * 128, n0 = blockIdx.y * 128;
  const int lm = lane & 15, kb = lane >> 4;

  const int srow = lane >> 2;
  // pre-swizzled global granule: slot (lane&3) gets granule (lane&3)^(srow&3)
  const int scol = (((lane & 3) ^ (srow & 3)) * 8);
  const int chunk0 = wid * 2, chunk1 = wid * 2 + 1;
  const int row0 = chunk0 * 16 + srow, row1 = chunk1 * 16 + srow;
  const int rg = (kb ^ (lm & 3)) * 8;   // read-granule half-offset

  // epilogue scalar loads FIRST (oldest in vmcnt FIFO; drain at first wait)
  float ev[4], xs4[4][4];
#pragma unroll
  for (int ni = 0; ni < 4; ++ni) ev[ni] = esq[n0 + wn * 64 + ni * 16 + lm];
#pragma unroll
  for (int mi = 0; mi < 4; ++mi)
#pragma unroll
    for (int r = 0; r < 4; ++r)
      xs4[mi][r] = xsq[m0 + wm * 64 + mi * 16 + kb * 4 + r];
  __builtin_amdgcn_sched_barrier(0);

#define SA(b) ((_Float16*)(smem + (b) * 16384))
#define SB(b) ((_Float16*)(smem + (b) * 16384 + 8192))
#define STAGE(ks, buf) do {                                                   \
    const int kc_ = (ks) * 32 + scol;                                         \
    GLOAD16(xh + (size_t)(m0 + row0) * CC + kc_, SA(buf) + chunk0 * 512);     \
    GLOAD16(eh + (size_t)(n0 + row0) * CC + kc_, SB(buf) + chunk0 * 512);     \
    GLOAD16(xh + (size_t)(m0 + row1) * CC + kc_, SA(buf) + chunk1 * 512);     \
    GLOAD16(eh + (size_t)(n0 + row1) * CC + kc_, SB(buf) + chunk1 * 512);     \
  } while (0)

  f32x4 acc[4][4] = {};
  STAGE(0, 0);
  STAGE(1, 1);
#pragma unroll
  for (int ks = 0; ks < 8; ++ks) {
    const int cur = ks % 3;
    if (ks < 7) {
      asm volatile("s_waitcnt vmcnt(4) lgkmcnt(0)" ::: "memory");
    } else {
      asm volatile("s_waitcnt vmcnt(0) lgkmcnt(0)" ::: "memory");
    }
    __builtin_amdgcn_s_barrier();
    __builtin_amdgcn_sched_barrier(0);     // nothing crosses the barrier

    if (ks < 6) STAGE(ks + 2, (ks + 2) % 3);   // safe: buf read at ks-1 drained

    half8 a[4], bfr[4];
#pragma unroll
    for (int i = 0; i < 4; ++i) {
      a[i]   = *(const half8*)&SA(cur)[(wm * 64 + i * 16 + lm) * 32 + rg];
      bfr[i] = *(const half8*)&SB(cur)[(wn * 64 + i * 16 + lm) * 32 + rg];
    }
#pragma unroll
    for (int mi = 0; mi < 4; ++mi)
#pragma unroll
      for (int ni = 0; ni < 4; ++ni)
        acc[mi][ni] = __builtin_amdgcn_mfma_f32_16x16x32_f16(a[mi], bfr[ni], acc[mi][ni], 0, 0, 0);
  }
#undef STAGE

  // ---- single post-loop barrier: iter-7 buf1 reads drain block-wide ------
  asm volatile("s_waitcnt lgkmcnt(0)" ::: "memory");
  __builtin_amdgcn_s_barrier();
  __builtin_amdgcn_sched_barrier(0);

  // ---- wave-private epilogue: ZERO barriers ------------------------------
  float* slice = (float*)(smem + wid * 8192);   // own 32x64 fp32 scratch
  const int swz = kb << 4;

#pragma unroll
  for (int ch = 0; ch < 2; ++ch) {
    if (ch) {  // own phase-B reads of chunk 0 retired before overwrite
      asm volatile("s_waitcnt lgkmcnt(0)" ::: "memory");
      __builtin_amdgcn_sched_barrier(0);
    }
    // phase A: own acc -> own slice (kb-XOR swizzle, 2 lanes/bank = free)
#pragma unroll
    for (int mh = 0; mh < 2; ++mh) {
      const int mi = ch * 2 + mh;
#pragma unroll
      for (int r = 0; r < 4; ++r) {
        const int lr = mh * 16 + kb * 4 + r;
#pragma unroll
        for (int ni = 0; ni < 4; ++ni) {
          float t1 = xs4[mi][r] + ev[ni];                    // fl(xsq+esq)
          float d = t1 - acc[mi][ni][r] * 4.8828125e-4f;     // exact 2^-11
          slice[lr * 64 + ((ni * 16 + lm) ^ swz)] = d;
        }
      }
    }
    asm volatile("s_waitcnt lgkmcnt(0)" ::: "memory");       // wave-local only
    __builtin_amdgcn_sched_barrier(0);
    // phase B: 8 its x 4 rows; 256B-contiguous NT stores + fused top-2
#pragma unroll
    for (int it = 0; it < 8; ++it) {
      const int lr = it * 4 + kb;                 // writer kb for row = it&3
      const int c = lm * 4;
      const f32x4 v = *(const f32x4*)&slice[lr * 64 + (c ^ ((it & 3) << 4))];
      const int gm = m0 + wm * 64 + ch * 32 + lr;
      __builtin_nontemporal_store(v,
          (f32x4*)(out + MM + (size_t)gm * (size_t)KK + n0 + wn * 64 + c));
      float s1 = 3.4e38f, s2 = 3.4e38f;
      int q1 = 0x7fffffff;
#pragma unroll
      for (int e = 0; e < 4; ++e) {
        const float d = v[e];
        const int q = n0 + wn * 64 + c + e;
        if (d < s1 || (d == s1 && q < q1)) { s2 = s1; s1 = d; q1 = q; }
        else s2 = fminf(s2, d);
      }
#pragma unroll
      for (int off = 1; off < 16; off <<= 1) {
        float o1 = __shfl_xor(s1, off), o2 = __shfl_xor(s2, off);
        int oq = __shfl_xor(q1, off);
        float mx = fmaxf(s1, o1);
        if (o1 < s1 || (o1 == s1 && oq < q1)) { s1 = o1; q1 = oq; }
        s2 = fminf(fminf(s2, o2), mx);
      }
      if (lm == 0) {
        const size_t pidx = (size_t)gm * 64 + blockIdx.y * 2 + wn;
        ps1[pidx] = s1; pi1[pidx] = q1; ps2[pidx] = s2;
      }
    }
  }
#undef SA
#undef SB
}

// ---------------------------------------------------------------------------
// Finish: merge 64 partials/row; accept if gap > MARGIN, else inline rescue
// (re-read row distances, screen, numpy-fp32 emulate, argmin).
// grid 4096, block 256 (wave per row), fully wave-local.
__global__ void vq_finish(const float* __restrict__ ps1, const int* __restrict__ pi1,
                          const float* __restrict__ ps2, const float* __restrict__ dist,
                          const float* __restrict__ x, const float* __restrict__ emb,
                          const float* __restrict__ xsq, const float* __restrict__ esq,
                          float* __restrict__ out) {
  __shared__ float xr[4][CC];
  __shared__ int cq[4][64];
  __shared__ int cnt[4];
  const int lane = threadIdx.x & 63, w = threadIdx.x >> 6;
  const int m = blockIdx.x * 4 + w;

  const size_t base = (size_t)m * 64 + lane;
  float s1 = ps1[base], s2 = ps2[base];
  int q1 = pi1[base];
#pragma unroll
  for (int off = 1; off < 64; off <<= 1) {
    float o1 = __shfl_xor(s1, off), o2 = __shfl_xor(s2, off);
    int oq = __shfl_xor(q1, off);
    float mx = fmaxf(s1, o1);
    if (o1 < s1 || (o1 == s1 && oq < q1)) { s1 = o1; q1 = oq; }
    s2 = fminf(fminf(s2, o2), mx);
  }

  if (s2 - s1 > MARGIN) {
    if (lane == 0) out[m] = (float)q1;
    return;
  }

  // rescue (rare): stage x row, screen candidates, exact fp32-chain emulation
  const int b = m >> 12, l = m & 4095;
#pragma unroll
  for (int j = 0; j < 4; ++j)
    xr[w][lane * 4 + j] = x[((size_t)b * CC + lane * 4 + j) * LL + l];
  if (lane == 0) cnt[w] = 0;

  const float thr = s1 + MARGIN;
  const float4* d4 = (const float4*)(dist + (size_t)m * KK);
  for (int i = 0; i < 16; ++i) {
    float4 v = d4[i * 64 + lane];
    float vv[4] = {v.x, v.y, v.z, v.w};
#pragma unroll
    for (int e = 0; e < 4; ++e)
      if (vv[e] <= thr) {
        int slot = atomicAdd(&cnt[w], 1);
        if (slot < 64) cq[w][slot] = (i * 64 + lane) * 4 + e;
      }
  }
  const int nc = min(cnt[w], 64);
  float bs = 3.4e38f;
  int bq = 0x7fffffff;
  if (lane < nc) {
    const int q = cq[w][lane];
    const float* e = emb + (size_t)q * CC;
    float a = 0.f;                         // BLAS-style sequential fp32 chain
    for (int c = 0; c < CC; ++c) a = fmaf(xr[w][c], e[c], a);
    float t1 = xsq[m] + esq[q];            // fl(x_sq + e_sq)
    bs = t1 - 2.0f * a;                    // fl(t1 - 2*dot)
    bq = q;
  }
#pragma unroll
  for (int off = 1; off < 64; off <<= 1) {
    float os = __shfl_xor(bs, off);
    int oq = __shfl_xor(bq, off);
    if (os < bs || (os == bs && oq < bq)) { bs = os; bq = oq; }
  }
  if (lane == 0) out[m] = (float)bq;
}

// ---------------------------------------------------------------------------
extern "C" void kernel_launch(void* const* d_in, const int* in_sizes, int n_in,
                              void* d_out, int out_size, void* d_ws, size_t ws_size,
                              hipStream_t stream) {
  const float* x = (const float*)d_in[0];
  const float* emb = (const float*)d_in[1];
  float* out = (float*)d_out;
  char* ws = (char*)d_ws;

  _Float16* xh = (_Float16*)(ws + 0);          // 8 MB
  _Float16* eh = (_Float16*)(ws + 8388608);    // 2 MB
  float* xsq = (float*)(ws + 10485760);        // 64 KB
  float* esq = (float*)(ws + 10551296);        // 16 KB
  float* ps1 = (float*)(ws + 10567680);        // 4 MB
  int*   pi1 = (int*)(ws + 14761984);          // 4 MB
  float* ps2 = (float*)(ws + 18956288);        // 4 MB

  vq_prep<<<1536, 256, 0, stream>>>(x, emb, xh, xsq, eh, esq);
  vq_gemm<<<dim3(128, 32), 256, 0, stream>>>(xh, eh, xsq, esq, out, ps1, pi1, ps2);
  vq_finish<<<4096, 256, 0, stream>>>(ps1, pi1, ps2, out + MM, x, emb, xsq, esq, out);
}

// Round 17
// 127.014 us; speedup vs baseline: 1.4028x; 1.4028x over previous
//
#include <hip/hip_runtime.h>
#include <hip/hip_fp16.h>

// Problem constants
#define BB 4
#define CC 256
#define LL 4096
#define MM 16384   // BB*LL rows
#define KK 4096    // codebook size
#define MARGIN 1.0e-4f

typedef _Float16 half8 __attribute__((ext_vector_type(8)));
typedef _Float16 half4_ __attribute__((ext_vector_type(4)));
typedef float f32x4 __attribute__((ext_vector_type(4)));

#define GLOAD16(gp, lp) __builtin_amdgcn_global_load_lds( \
    (const __attribute__((address_space(1))) void*)(gp),  \
    (__attribute__((address_space(3))) void*)(lp), 16, 0, 0)

// ---------------------------------------------------------------------------
// Fused prep: blocks [0,512) transpose x -> xh fp16 + numpy xsq;
//             blocks [512,1536) pack eh fp16 + numpy esq.  block 256.
__global__ void vq_prep(const float* __restrict__ x, const float* __restrict__ emb,
                        _Float16* __restrict__ xh, float* __restrict__ xsq,
                        _Float16* __restrict__ eh, float* __restrict__ esq) {
  __shared__ float tl[32][260];
  const int t = threadIdx.x;
  if (blockIdx.x < 512) {
    const int b = blockIdx.x >> 7, l0 = (blockIdx.x & 127) * 32;
    const float* src = x + (size_t)b * CC * LL + l0;
#pragma unroll
    for (int it = 0; it < 32; ++it) {
      const int idx = it * 256 + t;
      const int c = idx >> 5, l = idx & 31;
      tl[l][c] = src[(size_t)c * LL + l];
    }
    __syncthreads();
#pragma unroll
    for (int it = 0; it < 4; ++it) {
      const int u = it * 256 + t;
      const int l = u >> 5, c8 = (u & 31) * 8;
      half8 h;
#pragma unroll
      for (int j = 0; j < 8; ++j) h[j] = (_Float16)tl[l][c8 + j];
      *(half8*)(xh + ((size_t)(b * LL + l0 + l)) * CC + c8) = h;
    }
    if (t < 32) {
      float S[2];
#pragma unroll
      for (int blk = 0; blk < 2; ++blk) {
        float v[16];
#pragma unroll
        for (int ln = 0; ln < 16; ++ln) {
          float q[8];
#pragma unroll
          for (int j = 0; j < 8; ++j) {
            const float xv = tl[t][blk * 128 + j * 16 + ln];
            q[j] = xv * xv;
          }
          v[ln] = ((q[0] + q[1]) + (q[2] + q[3])) + ((q[4] + q[5]) + (q[6] + q[7]));
        }
        float s1[8], s2[4], s3[2];
#pragma unroll
        for (int ln = 0; ln < 8; ++ln) s1[ln] = v[ln] + v[ln + 8];
#pragma unroll
        for (int ln = 0; ln < 4; ++ln) s2[ln] = s1[ln] + s1[ln + 4];
#pragma unroll
        for (int ln = 0; ln < 2; ++ln) s3[ln] = s2[ln] + s2[ln + 2];
        S[blk] = s3[0] + s3[1];
      }
      xsq[b * LL + l0 + t] = S[0] + S[1];
    }
  } else {
    const int lane = t & 63, w = t >> 6;
    const int q = (blockIdx.x - 512) * 4 + w;
    const float4 v = ((const float4*)(emb + (size_t)q * CC))[lane];
    float vv[4] = {v.x, v.y, v.z, v.w};
    _Float16 h[4];
#pragma unroll
    for (int i = 0; i < 4; ++i) h[i] = (_Float16)(vv[i] * 4096.0f);
    *(half4_*)(eh + (size_t)q * CC + lane * 4) = half4_{h[0], h[1], h[2], h[3]};
    if (lane == 0) {
      const float* pe = emb + (size_t)q * CC;
      float S[2];
#pragma unroll
      for (int blk = 0; blk < 2; ++blk) {
        float vt[16];
#pragma unroll
        for (int ln = 0; ln < 16; ++ln) {
          float qq[8];
#pragma unroll
          for (int j = 0; j < 8; ++j) {
            const float ev = pe[blk * 128 + j * 16 + ln];
            qq[j] = ev * ev;
          }
          vt[ln] = ((qq[0] + qq[1]) + (qq[2] + qq[3])) + ((qq[4] + qq[5]) + (qq[6] + qq[7]));
        }
        float s1[8], s2[4], s3[2];
#pragma unroll
        for (int ln = 0; ln < 8; ++ln) s1[ln] = vt[ln] + vt[ln + 8];
#pragma unroll
        for (int ln = 0; ln < 4; ++ln) s2[ln] = s1[ln] + s1[ln + 4];
#pragma unroll
        for (int ln = 0; ln < 2; ++ln) s3[ln] = s2[ln] + s2[ln + 2];
        S[blk] = s3[0] + s3[1];
      }
      esq[q] = S[0] + S[1];
    }
  }
}

// ---------------------------------------------------------------------------
// GEMM (r13 base, single-barrier K-loop + bank-swizzled fragments):
// 128x128 tile, 4 waves, 3 rotating 16KB LDS buffers (depth-2), counted
// vmcnt, ONE barrier per K-step (lgkmcnt(0) before it; STAGE after it).
// LDS granule swizzle: slot c^(r&3) via pre-swizzled global source (same
// 64B segment per 4-lane group -> coalescing unchanged); reads use
// kb^(lm&3) -> 8-way -> 4-way bank conflicts. Epilogue: LDS-transposed
// coalesced NT stores + fused top-2, DS-only barriers.
// grid (M/128, K/128) = (128, 32), block 256 (4 waves, 2x2)
__global__ __launch_bounds__(256) void vq_gemm(
    const _Float16* __restrict__ xh, const _Float16* __restrict__ eh,
    const float* __restrict__ xsq, const float* __restrict__ esq,
    float* __restrict__ out,
    float* __restrict__ ps1, int* __restrict__ pi1, float* __restrict__ ps2) {
  __shared__ __align__(16) char smem[49152];
  float* sOut = (float*)smem;   // 16KB epilogue alias (buf0 region)

  const int t = threadIdx.x, lane = t & 63, wid = t >> 6;
  const int wm = wid >> 1, wn = wid & 1;
  const int m0 = blockIdx.x * 128, n0 = blockIdx.y * 128;
  const int lm = lane & 15, kb = lane >> 4;

  const int srow = lane >> 2;
  // pre-swizzled global granule: slot (lane&3) gets granule (lane&3)^(srow&3)
  const int scol = (((lane & 3) ^ (srow & 3)) * 8);
  const int chunk0 = wid * 2, chunk1 = wid * 2 + 1;
  const int row0 = chunk0 * 16 + srow, row1 = chunk1 * 16 + srow;
  const int rg = (kb ^ (lm & 3)) * 8;   // read-granule half-offset

  // epilogue scalar loads FIRST (oldest in vmcnt FIFO; drain at first wait)
  float ev[4], xs4[4][4];
#pragma unroll
  for (int ni = 0; ni < 4; ++ni) ev[ni] = esq[n0 + wn * 64 + ni * 16 + lm];
#pragma unroll
  for (int mi = 0; mi < 4; ++mi)
#pragma unroll
    for (int r = 0; r < 4; ++r)
      xs4[mi][r] = xsq[m0 + wm * 64 + mi * 16 + kb * 4 + r];
  __builtin_amdgcn_sched_barrier(0);

#define SA(b) ((_Float16*)(smem + (b) * 16384))
#define SB(b) ((_Float16*)(smem + (b) * 16384 + 8192))
#define STAGE(ks, buf) do {                                                   \
    const int kc_ = (ks) * 32 + scol;                                         \
    GLOAD16(xh + (size_t)(m0 + row0) * CC + kc_, SA(buf) + chunk0 * 512);     \
    GLOAD16(eh + (size_t)(n0 + row0) * CC + kc_, SB(buf) + chunk0 * 512);     \
    GLOAD16(xh + (size_t)(m0 + row1) * CC + kc_, SA(buf) + chunk1 * 512);     \
    GLOAD16(eh + (size_t)(n0 + row1) * CC + kc_, SB(buf) + chunk1 * 512);     \
  } while (0)

  f32x4 acc[4][4] = {};
  STAGE(0, 0);
  STAGE(1, 1);
#pragma unroll
  for (int ks = 0; ks < 8; ++ks) {
    const int cur = ks % 3;
    // own prev-iter ds_reads retired + own ks-tile landed, then barrier:
    // transitively, all waves' (ks-1) reads done AND all ks-chunks in LDS.
    if (ks < 7) {
      asm volatile("s_waitcnt vmcnt(4) lgkmcnt(0)" ::: "memory");
    } else {
      asm volatile("s_waitcnt vmcnt(0) lgkmcnt(0)" ::: "memory");
    }
    __builtin_amdgcn_s_barrier();
    __builtin_amdgcn_sched_barrier(0);     // nothing crosses the barrier

    if (ks < 6) STAGE(ks + 2, (ks + 2) % 3);   // safe: buf read at ks-1 drained

    half8 a[4], bfr[4];
#pragma unroll
    for (int i = 0; i < 4; ++i) {
      a[i]   = *(const half8*)&SA(cur)[(wm * 64 + i * 16 + lm) * 32 + rg];
      bfr[i] = *(const half8*)&SB(cur)[(wn * 64 + i * 16 + lm) * 32 + rg];
    }
#pragma unroll
    for (int mi = 0; mi < 4; ++mi)
#pragma unroll
      for (int ni = 0; ni < 4; ++ni)
        acc[mi][ni] = __builtin_amdgcn_mfma_f32_16x16x32_f16(a[mi], bfr[ni], acc[mi][ni], 0, 0, 0);
  }
#undef STAGE

  // ---- epilogue: per mi-chunk (32 rows x 128 cols), DS-only barriers -----
  // phase A writes buf0 region; iter-7 reads used buf1 (disjoint); all waves'
  // iter-6 (buf0) reads were drained by barrier_7.
#define EPI_BAR() do {                                          \
    asm volatile("s_waitcnt lgkmcnt(0)" ::: "memory");          \
    __builtin_amdgcn_s_barrier();                               \
    __builtin_amdgcn_sched_barrier(0);                          \
  } while (0)

  const int swz = kb << 4;
  const int erow = t >> 3, ej = t & 7;            // phase-B: row 0..31, sub 0..7
  const int esw = ((erow >> 2) & 3) << 4;
  const int egm0 = m0 + (erow >> 4) * 64 + (erow & 15);

#pragma unroll
  for (int mi = 0; mi < 4; ++mi) {
    // phase A: compute d, swizzled LDS write
#pragma unroll
    for (int r = 0; r < 4; ++r) {
      const int row = wm * 16 + kb * 4 + r;
#pragma unroll
      for (int ni = 0; ni < 4; ++ni) {
        float t1 = xs4[mi][r] + ev[ni];                      // fl(xsq+esq)
        float d = t1 - acc[mi][ni][r] * 4.8828125e-4f;       // exact 2^-11 scale
        sOut[row * 128 + ((wn * 64 + ni * 16 + lm) ^ swz)] = d;
      }
    }
    EPI_BAR();
    // phase B: coalesced NT store + fused top-2 (8 threads per row)
    float s1 = 3.4e38f, s2 = 3.4e38f;
    int q1 = 0x7fffffff;
    const int gm = egm0 + mi * 16;
#pragma unroll
    for (int i = 0; i < 4; ++i) {
      const int c = 4 * ej + 32 * i;              // dword col within 128
      const f32x4 v = *(const f32x4*)&sOut[erow * 128 + (c ^ esw)];
      __builtin_nontemporal_store(v, (f32x4*)(out + MM + (size_t)gm * (size_t)KK + n0 + c));
#pragma unroll
      for (int e = 0; e < 4; ++e) {
        const float d = v[e];
        const int q = n0 + c + e;
        if (d < s1 || (d == s1 && q < q1)) { s2 = s1; s1 = d; q1 = q; }
        else s2 = fminf(s2, d);
      }
    }
#pragma unroll
    for (int off = 1; off < 8; off <<= 1) {
      float o1 = __shfl_xor(s1, off), o2 = __shfl_xor(s2, off);
      int oq = __shfl_xor(q1, off);
      float mx = fmaxf(s1, o1);
      if (o1 < s1 || (o1 == s1 && oq < q1)) { s1 = o1; q1 = oq; }
      s2 = fminf(fminf(s2, o2), mx);
    }
    if (ej == 0) {
      const size_t pidx = (size_t)gm * 32 + blockIdx.y;
      ps1[pidx] = s1; pi1[pidx] = q1; ps2[pidx] = s2;
    }
    if (mi < 3) EPI_BAR();                        // sOut reads done before next A
  }
#undef EPI_BAR
#undef SA
#undef SB
}

// ---------------------------------------------------------------------------
// Finish: merge 32 partials/row; accept if gap > MARGIN, else inline rescue
// (re-read row distances, screen, numpy-fp32 emulate, argmin).
// grid 4096, block 256 (wave per row), fully wave-local.
__global__ void vq_finish(const float* __restrict__ ps1, const int* __restrict__ pi1,
                          const float* __restrict__ ps2, const float* __restrict__ dist,
                          const float* __restrict__ x, const float* __restrict__ emb,
                          const float* __restrict__ xsq, const float* __restrict__ esq,
                          float* __restrict__ out) {
  __shared__ float xr[4][CC];
  __shared__ int cq[4][64];
  __shared__ int cnt[4];
  const int lane = threadIdx.x & 63, w = threadIdx.x >> 6;
  const int m = blockIdx.x * 4 + w;

  float s1 = 3.4e38f, s2 = 3.4e38f;
  int q1 = 0x7fffffff;
  if (lane < 32) {
    const size_t base = (size_t)m * 32 + lane;
    s1 = ps1[base]; s2 = ps2[base]; q1 = pi1[base];
  }
#pragma unroll
  for (int off = 1; off < 32; off <<= 1) {
    float o1 = __shfl_xor(s1, off), o2 = __shfl_xor(s2, off);
    int oq = __shfl_xor(q1, off);
    float mx = fmaxf(s1, o1);
    if (o1 < s1 || (o1 == s1 && oq < q1)) { s1 = o1; q1 = oq; }
    s2 = fminf(fminf(s2, o2), mx);
  }
  s1 = __shfl(s1, 0); s2 = __shfl(s2, 0); q1 = __shfl(q1, 0);

  if (s2 - s1 > MARGIN) {
    if (lane == 0) out[m] = (float)q1;
    return;
  }

  // rescue (rare): stage x row, screen candidates, exact fp32-chain emulation
  const int b = m >> 12, l = m & 4095;
#pragma unroll
  for (int j = 0; j < 4; ++j)
    xr[w][lane * 4 + j] = x[((size_t)b * CC + lane * 4 + j) * LL + l];
  if (lane == 0) cnt[w] = 0;

  const float thr = s1 + MARGIN;
  const float4* d4 = (const float4*)(dist + (size_t)m * KK);
  for (int i = 0; i < 16; ++i) {
    float4 v = d4[i * 64 + lane];
    float vv[4] = {v.x, v.y, v.z, v.w};
#pragma unroll
    for (int e = 0; e < 4; ++e)
      if (vv[e] <= thr) {
        int slot = atomicAdd(&cnt[w], 1);
        if (slot < 64) cq[w][slot] = (i * 64 + lane) * 4 + e;
      }
  }
  const int nc = min(cnt[w], 64);
  float bs = 3.4e38f;
  int bq = 0x7fffffff;
  if (lane < nc) {
    const int q = cq[w][lane];
    const float* e = emb + (size_t)q * CC;
    float a = 0.f;                         // BLAS-style sequential fp32 chain
    for (int c = 0; c < CC; ++c) a = fmaf(xr[w][c], e[c], a);
    float t1 = xsq[m] + esq[q];            // fl(x_sq + e_sq)
    bs = t1 - 2.0f * a;                    // fl(t1 - 2*dot)
    bq = q;
  }
#pragma unroll
  for (int off = 1; off < 64; off <<= 1) {
    float os = __shfl_xor(bs, off);
    int oq = __shfl_xor(bq, off);
    if (os < bs || (os == bs && oq < bq)) { bs = os; bq = oq; }
  }
  if (lane == 0) out[m] = (float)bq;
}

// ---------------------------------------------------------------------------
extern "C" void kernel_launch(void* const* d_in, const int* in_sizes, int n_in,
                              void* d_out, int out_size, void* d_ws, size_t ws_size,
                              hipStream_t stream) {
  const float* x = (const float*)d_in[0];
  const float* emb = (const float*)d_in[1];
  float* out = (float*)d_out;
  char* ws = (char*)d_ws;

  _Float16* xh = (_Float16*)(ws + 0);          // 8 MB
  _Float16* eh = (_Float16*)(ws + 8388608);    // 2 MB
  float* xsq = (float*)(ws + 10485760);        // 64 KB
  float* esq = (float*)(ws + 10551296);        // 16 KB
  float* ps1 = (float*)(ws + 10567680);        // 2 MB
  int*   pi1 = (int*)(ws + 12664832);          // 2 MB
  float* ps2 = (float*)(ws + 14761984);        // 2 MB

  vq_prep<<<1536, 256, 0, stream>>>(x, emb, xh, xsq, eh, esq);
  vq_gemm<<<dim3(128, 32), 256, 0, stream>>>(xh, eh, xsq, esq, out, ps1, pi1, ps2);
  vq_finish<<<4096, 256, 0, stream>>>(ps1, pi1, ps2, out + MM, x, emb, xsq, esq, out);
}